// Round 2
// baseline (7284.035 us; speedup 1.0000x reference)
//
#include <hip/hip_runtime.h>
#include <hip/hip_bf16.h>
#include <math.h>

#define DEVI __device__ __forceinline__
typedef __attribute__((ext_vector_type(8))) short bf16x8;
typedef __attribute__((ext_vector_type(4))) float f32x4;
typedef __attribute__((ext_vector_type(4))) short s16x4;

#define MFMA(a, b, c) __builtin_amdgcn_mfma_f32_16x16x32_bf16((a), (b), (c), 0, 0, 0)

DEVI short f2bf(float f) {
    unsigned u = __builtin_bit_cast(unsigned, f);
    return (short)((u + 0x7FFFu + ((u >> 16) & 1u)) >> 16);
}
DEVI float bf2f(short s) {
    unsigned u = ((unsigned)(unsigned short)s) << 16;
    return __builtin_bit_cast(float, u);
}
DEVI int swz(int row, int cb, int ld) { return row * ld + (cb ^ ((row & 7) << 4)); }

// fp32 -> bf16 weight pre-conversion (amortizes conversion across all 8192 blocks)
__global__ void prep_kernel(const float* __restrict__ s, short* __restrict__ d, int n4) {
    int i = blockIdx.x * 256 + threadIdx.x;
    if (i < n4) {
        f32x4 v = ((const f32x4*)s)[i];
        s16x4 o;
        o[0] = f2bf(v[0]); o[1] = f2bf(v[1]); o[2] = f2bf(v[2]); o[3] = f2bf(v[3]);
        ((s16x4*)d)[i] = o;
    }
}

// LDS map (75264 B total -> 2 blocks/CU):
//  [0,50176)    R0: sX fp32 [256][49] (gather->LN1). After LN1:
//               SW bf16 [49r][512B swz] @0 (normed win; later y=LN2 out)
//               chunk @25088: CQ(6272) CK(6272) CV(8192); SATT overlays CQ+CK
//  [50176,75264) OO: LN1 stats | O bf16 [49r][512B swz] | LN2 part/stats | H (MLP chunk)
__global__ __launch_bounds__(512, 4) void swin_kernel(
    const float* __restrict__ x,
    const float* __restrict__ n1w, const float* __restrict__ n1b,
    const short* __restrict__ WqB, const float* __restrict__ Bq,
    const short* __restrict__ WoB, const float* __restrict__ Bo,
    const float* __restrict__ n2w, const float* __restrict__ n2b,
    const short* __restrict__ W1B, const float* __restrict__ B1,
    const short* __restrict__ W2B, const float* __restrict__ B2,
    float* __restrict__ out)
{
    extern __shared__ __align__(16) char smem[];
    constexpr int SW = 0, CQ = 25088, CK = 31360, CV = 37632, OO = 50176;

    const int bid = blockIdx.x;
    const int b = bid >> 10, wh = (bid >> 5) & 31, w7 = bid & 31;
    const int tid = threadIdx.x, wv = tid >> 6, lane = tid & 63;
    const int lg = lane >> 4, l15 = lane & 15;
    const int c0 = wv * 32 + l15;      // this thread's ct=0 output column
    const f32x4 z = {0.f, 0.f, 0.f, 0.f};

    // ---------------- gather window -> sX[c][49] fp32 ----------------
    {
        float* sX = (float*)smem;
        const float* xb = x + (size_t)b * (256 * 224 * 224);
        for (int i = tid; i < 256 * 49; i += 512) {
            int c = i / 49, l = i - c * 49;
            int hh = wh * 7 + l / 7, ww = w7 * 7 + (l % 7);
            sX[i] = xb[((size_t)c * 224 + hh) * 224 + ww];
        }
    }
    __syncthreads();
    // ---------------- LN1 stats -> OO ----------------
    {
        const int l = tid >> 3, s = tid & 7;
        if (l < 49) {
            const float* sX = (const float*)smem;
            float sum = 0.f, sq = 0.f;
            for (int ii = 0; ii < 32; ++ii) {
                int c = s * 32 + ((ii + tid) & 31);
                float v = sX[c * 49 + l];
                sum += v; sq += v * v;
            }
#pragma unroll
            for (int m = 1; m < 8; m <<= 1) { sum += __shfl_xor(sum, m); sq += __shfl_xor(sq, m); }
            if (s == 0) {
                float mean = sum * (1.f / 256.f);
                ((float*)(smem + OO))[l * 2] = mean;
                ((float*)(smem + OO))[l * 2 + 1] = rsqrtf(sq * (1.f / 256.f) - mean * mean + 1e-5f);
            }
        }
    }
    __syncthreads();
    // ---------------- LN1 apply -> residual registers ----------------
    float resid[32];   // [ct*16 + mt*4 + r]: row = mt*16+lg*4+r, col = c0+ct*16
    {
        const float* sX = (const float*)smem;
        const float* st = (const float*)(smem + OO);
        float w0 = n1w[c0], b0 = n1b[c0], w1 = n1w[c0 + 16], b1 = n1b[c0 + 16];
#pragma unroll
        for (int ct = 0; ct < 2; ++ct)
#pragma unroll
        for (int mt = 0; mt < 4; ++mt)
#pragma unroll
        for (int r = 0; r < 4; ++r) {
            int row = mt * 16 + lg * 4 + r, col = c0 + ct * 16;
            float v = 0.f;
            if (row < 49)
                v = (sX[col * 49 + row] - st[row * 2]) * st[row * 2 + 1] * (ct ? w1 : w0) + (ct ? b1 : b0);
            resid[ct * 16 + mt * 4 + r] = v;
        }
    }
    __syncthreads();           // all sX reads done before SW overwrites it
    // write SW (bf16, swizzled)
#pragma unroll
    for (int ct = 0; ct < 2; ++ct)
#pragma unroll
    for (int mt = 0; mt < 4; ++mt)
#pragma unroll
    for (int r = 0; r < 4; ++r) {
        int row = mt * 16 + lg * 4 + r;
        if (row < 49)
            *(short*)(smem + SW + swz(row, (c0 + ct * 16) * 2, 512)) = f2bf(resid[ct * 16 + mt * 4 + r]);
    }
    __syncthreads();

    // ---------------- attention: 4 head-pair chunks ----------------
    const int grp = wv >> 2, mts = wv & 3;
    int arow = mts * 16 + l15; if (arow > 48) arow = 48;
#pragma unroll 1
    for (int hp = 0; hp < 4; ++hp) {
        // QKV GEMM for heads {2hp, 2hp+1}: 12 col-tiles; waves 0-3 take q+v, 4-7 take k
#pragma unroll 1
        for (int sub = 0; sub < 2; ++sub) {
            if (sub == 0 || wv < 4) {
                const int t = sub ? (8 + wv) : wv;
                const int part = t >> 2, tt = t & 3;
                const int lc = tt * 16 + l15;              // local col 0..63
                const int jw = part * 256 + hp * 64 + lc;  // qkv weight row
                f32x4 a0 = z, a1 = z, a2 = z, a3 = z;
                const short* wr = WqB + (size_t)jw * 256 + lg * 8;
#pragma unroll
                for (int kk = 0; kk < 8; ++kk) {
                    bf16x8 bw = *(const bf16x8*)(wr + kk * 32);
                    const int cb = kk * 64 + lg * 16;
                    bf16x8 f0 = *(const bf16x8*)(smem + SW + swz(l15, cb, 512));
                    bf16x8 f1 = *(const bf16x8*)(smem + SW + swz(16 + l15, cb, 512));
                    bf16x8 f2 = *(const bf16x8*)(smem + SW + swz(32 + l15, cb, 512));
                    bf16x8 f3 = *(const bf16x8*)(smem + SW + swz(48, cb, 512));
                    a0 = MFMA(f0, bw, a0); a1 = MFMA(f1, bw, a1);
                    a2 = MFMA(f2, bw, a2); a3 = MFMA(f3, bw, a3);
                }
                const float bias = Bq[jw];
                if (part < 2) {
                    char* base = smem + (part ? CK : CQ);
#pragma unroll
                    for (int mt = 0; mt < 4; ++mt) {
                        f32x4 av = (mt == 0) ? a0 : (mt == 1) ? a1 : (mt == 2) ? a2 : a3;
#pragma unroll
                        for (int r = 0; r < 4; ++r) {
                            int row = mt * 16 + lg * 4 + r;
                            if (row < 49) *(short*)(base + swz(row, lc * 2, 128)) = f2bf(av[r] + bias);
                        }
                    }
                } else {   // v, stored transposed vT[d][m]
#pragma unroll
                    for (int mt = 0; mt < 4; ++mt) {
                        f32x4 av = (mt == 0) ? a0 : (mt == 1) ? a1 : (mt == 2) ? a2 : a3;
#pragma unroll
                        for (int r = 0; r < 4; ++r) {
                            int row = mt * 16 + lg * 4 + r;
                            *(short*)(smem + CV + swz(lc, row * 2, 128)) = f2bf(av[r] + bias);
                        }
                    }
                }
            }
        }
        __syncthreads();
        // QK^T + softmax (fully in registers)
        const int hb = grp * 64 + lg * 16;
        f32x4 s0 = z, s1 = z, s2 = z, s3 = z;
        {
            bf16x8 qa = *(const bf16x8*)(smem + CQ + swz(arow, hb, 128));
            bf16x8 k0 = *(const bf16x8*)(smem + CK + swz(l15, hb, 128));
            bf16x8 k1 = *(const bf16x8*)(smem + CK + swz(16 + l15, hb, 128));
            bf16x8 k2 = *(const bf16x8*)(smem + CK + swz(32 + l15, hb, 128));
            bf16x8 k3 = *(const bf16x8*)(smem + CK + swz(48, hb, 128));
            s0 = MFMA(qa, k0, s0); s1 = MFMA(qa, k1, s1);
            s2 = MFMA(qa, k2, s2); s3 = MFMA(qa, k3, s3);
        }
        const float scale = 0.17677669529663687f;
        float pr[4][4];
#pragma unroll
        for (int rj = 0; rj < 4; ++rj) {
            float v0 = s0[rj] * scale, v1 = s1[rj] * scale;
            float v2 = s2[rj] * scale, v3 = s3[rj] * scale;
            const int c3 = 48 + l15;
            float mx = fmaxf(fmaxf(v0, v1), v2);
            if (c3 < 49) mx = fmaxf(mx, v3);
#pragma unroll
            for (int mm = 1; mm < 16; mm <<= 1) mx = fmaxf(mx, __shfl_xor(mx, mm));
            float e0 = __expf(v0 - mx), e1 = __expf(v1 - mx), e2 = __expf(v2 - mx);
            float e3 = (c3 < 49) ? __expf(v3 - mx) : 0.f;
            float sm = e0 + e1 + e2 + e3;
#pragma unroll
            for (int mm = 1; mm < 16; mm <<= 1) sm += __shfl_xor(sm, mm);
            float inv = 1.f / sm;
            pr[rj][0] = e0 * inv; pr[rj][1] = e1 * inv;
            pr[rj][2] = e2 * inv; pr[rj][3] = e3 * inv;
        }
        __syncthreads();    // q/k reads complete before satt overlays them
        char* satt = smem + 25088 + grp * 6272;
#pragma unroll
        for (int rj = 0; rj < 4; ++rj) {
            int row = mts * 16 + lg * 4 + rj;
            if (row < 49) {
                *(short*)(satt + swz(row, l15 * 2, 128)) = f2bf(pr[rj][0]);
                *(short*)(satt + swz(row, (16 + l15) * 2, 128)) = f2bf(pr[rj][1]);
                *(short*)(satt + swz(row, (32 + l15) * 2, 128)) = f2bf(pr[rj][2]);
                *(short*)(satt + swz(row, (48 + l15) * 2, 128)) = f2bf(pr[rj][3]);
            }
        }
        __syncthreads();
        // PV -> O columns [hp*64 + grp*32 .. +32)
        f32x4 o0 = z, o1 = z;
#pragma unroll
        for (int kk = 0; kk < 2; ++kk) {
            const int kb = kk * 64 + lg * 16;
            bf16x8 pa  = *(const bf16x8*)(satt + swz(arow, kb, 128));
            bf16x8 vb0 = *(const bf16x8*)(smem + CV + swz(grp * 32 + l15, kb, 128));
            bf16x8 vb1 = *(const bf16x8*)(smem + CV + swz(grp * 32 + 16 + l15, kb, 128));
            o0 = MFMA(pa, vb0, o0); o1 = MFMA(pa, vb1, o1);
        }
#pragma unroll
        for (int nt = 0; nt < 2; ++nt) {
            f32x4 ov = nt ? o1 : o0;
#pragma unroll
            for (int r = 0; r < 4; ++r) {
                int row = mts * 16 + lg * 4 + r;
                if (row < 49) {
                    int col = hp * 64 + grp * 32 + nt * 16 + l15;
                    *(short*)(smem + OO + swz(row, col * 2, 512)) = f2bf(ov[r]);
                }
            }
        }
        __syncthreads();
    }

    // ---------------- out-proj + residual (into regs) ----------------
#pragma unroll 1
    for (int ct = 0; ct < 2; ++ct) {
        const int j = c0 + ct * 16;
        f32x4 a0 = z, a1 = z, a2 = z, a3 = z;
        const short* wr = WoB + (size_t)j * 256 + lg * 8;
#pragma unroll
        for (int kk = 0; kk < 8; ++kk) {
            bf16x8 bw = *(const bf16x8*)(wr + kk * 32);
            const int cb = kk * 64 + lg * 16;
            bf16x8 f0 = *(const bf16x8*)(smem + OO + swz(l15, cb, 512));
            bf16x8 f1 = *(const bf16x8*)(smem + OO + swz(16 + l15, cb, 512));
            bf16x8 f2 = *(const bf16x8*)(smem + OO + swz(32 + l15, cb, 512));
            bf16x8 f3 = *(const bf16x8*)(smem + OO + swz(48, cb, 512));
            a0 = MFMA(f0, bw, a0); a1 = MFMA(f1, bw, a1);
            a2 = MFMA(f2, bw, a2); a3 = MFMA(f3, bw, a3);
        }
        const float bias = Bo[j];
#pragma unroll
        for (int mt = 0; mt < 4; ++mt) {
            f32x4 av = (mt == 0) ? a0 : (mt == 1) ? a1 : (mt == 2) ? a2 : a3;
#pragma unroll
            for (int r = 0; r < 4; ++r) {
                int row = mt * 16 + lg * 4 + r;
                if (row < 49) resid[ct * 16 + mt * 4 + r] += av[r] + bias;
            }
        }
    }
    __syncthreads();
    // ---------------- LN2 (stats via shfl + small LDS partials) ----------
    {
        float* part  = (float*)(smem + OO);
        float* part2 = (float*)(smem + OO + 2048);
#pragma unroll
        for (int mt = 0; mt < 4; ++mt)
#pragma unroll
        for (int r = 0; r < 4; ++r) {
            float a = resid[mt * 4 + r], c = resid[16 + mt * 4 + r];
            float sv = a + c, qv = a * a + c * c;
#pragma unroll
            for (int mm = 1; mm < 16; mm <<= 1) { sv += __shfl_xor(sv, mm); qv += __shfl_xor(qv, mm); }
            if (l15 == 0) {
                int row = mt * 16 + lg * 4 + r;
                part[row * 8 + wv] = sv; part2[row * 8 + wv] = qv;
            }
        }
    }
    __syncthreads();
    if (tid < 64) {
        float* part = (float*)(smem + OO); float* part2 = (float*)(smem + OO + 2048);
        float s = 0.f, q = 0.f;
#pragma unroll
        for (int w = 0; w < 8; ++w) { s += part[tid * 8 + w]; q += part2[tid * 8 + w]; }
        float mean = s * (1.f / 256.f);
        float* st = (float*)(smem + OO + 4096);
        st[tid * 2] = mean;
        st[tid * 2 + 1] = rsqrtf(q * (1.f / 256.f) - mean * mean + 1e-5f);
    }
    __syncthreads();
    {
        const float* st = (const float*)(smem + OO + 4096);
        float w0 = n2w[c0], b0 = n2b[c0], w1 = n2w[c0 + 16], b1 = n2b[c0 + 16];
#pragma unroll
        for (int ct = 0; ct < 2; ++ct)
#pragma unroll
        for (int mt = 0; mt < 4; ++mt)
#pragma unroll
        for (int r = 0; r < 4; ++r) {
            int row = mt * 16 + lg * 4 + r;
            if (row < 49) {
                float yv = (resid[ct * 16 + mt * 4 + r] - st[row * 2]) * st[row * 2 + 1] * (ct ? w1 : w0) + (ct ? b1 : b0);
                *(short*)(smem + SW + swz(row, (c0 + ct * 16) * 2, 512)) = f2bf(yv);
            }
        }
    }
    __syncthreads();
    // ---------------- MLP: 4 hidden chunks of 256 ----------------
#pragma unroll 1
    for (int chunk = 0; chunk < 4; ++chunk) {
#pragma unroll 1
        for (int ct = 0; ct < 2; ++ct) {
            const int lcol = c0 + ct * 16;
            const int jj = chunk * 256 + lcol;
            f32x4 a0 = z, a1 = z, a2 = z, a3 = z;
            const short* wr = W1B + (size_t)jj * 256 + lg * 8;
#pragma unroll
            for (int kk = 0; kk < 8; ++kk) {
                bf16x8 bw = *(const bf16x8*)(wr + kk * 32);
                const int cb = kk * 64 + lg * 16;
                bf16x8 f0 = *(const bf16x8*)(smem + SW + swz(l15, cb, 512));
                bf16x8 f1 = *(const bf16x8*)(smem + SW + swz(16 + l15, cb, 512));
                bf16x8 f2 = *(const bf16x8*)(smem + SW + swz(32 + l15, cb, 512));
                bf16x8 f3 = *(const bf16x8*)(smem + SW + swz(48, cb, 512));
                a0 = MFMA(f0, bw, a0); a1 = MFMA(f1, bw, a1);
                a2 = MFMA(f2, bw, a2); a3 = MFMA(f3, bw, a3);
            }
            const float bias = B1[jj];
#pragma unroll
            for (int mt = 0; mt < 4; ++mt) {
                f32x4 av = (mt == 0) ? a0 : (mt == 1) ? a1 : (mt == 2) ? a2 : a3;
#pragma unroll
                for (int r = 0; r < 4; ++r) {
                    int row = mt * 16 + lg * 4 + r;
                    if (row < 49) {
                        float v = av[r] + bias;
                        float g = 0.5f * v * (1.f + erff(v * 0.70710678118654752f));
                        *(short*)(smem + OO + swz(row, lcol * 2, 512)) = f2bf(g);
                    }
                }
            }
        }
        __syncthreads();
#pragma unroll 1
        for (int ct = 0; ct < 2; ++ct) {
            const int j = c0 + ct * 16;
            f32x4 a0 = z, a1 = z, a2 = z, a3 = z;
            const short* wr = W2B + (size_t)j * 1024 + chunk * 256 + lg * 8;
#pragma unroll
            for (int kk = 0; kk < 8; ++kk) {
                bf16x8 bw = *(const bf16x8*)(wr + kk * 32);
                const int cb = kk * 64 + lg * 16;
                bf16x8 f0 = *(const bf16x8*)(smem + OO + swz(l15, cb, 512));
                bf16x8 f1 = *(const bf16x8*)(smem + OO + swz(16 + l15, cb, 512));
                bf16x8 f2 = *(const bf16x8*)(smem + OO + swz(32 + l15, cb, 512));
                bf16x8 f3 = *(const bf16x8*)(smem + OO + swz(48, cb, 512));
                a0 = MFMA(f0, bw, a0); a1 = MFMA(f1, bw, a1);
                a2 = MFMA(f2, bw, a2); a3 = MFMA(f3, bw, a3);
            }
#pragma unroll
            for (int mt = 0; mt < 4; ++mt) {
                f32x4 av = (mt == 0) ? a0 : (mt == 1) ? a1 : (mt == 2) ? a2 : a3;
#pragma unroll
                for (int r = 0; r < 4; ++r) {
                    int row = mt * 16 + lg * 4 + r;
                    if (row < 49) resid[ct * 16 + mt * 4 + r] += av[r];
                }
            }
        }
        __syncthreads();
    }
    // ---------------- final: +b2, stage fp32, window-reverse scatter ------
    {
        float b20 = B2[c0], b21 = B2[c0 + 16];
#pragma unroll
        for (int ct = 0; ct < 2; ++ct)
#pragma unroll
        for (int mt = 0; mt < 4; ++mt)
#pragma unroll
        for (int r = 0; r < 4; ++r) {
            int row = mt * 16 + lg * 4 + r;
            if (row < 49) {
                int col = c0 + ct * 16;
                *(float*)(smem + row * 1024 + ((col * 4) ^ ((row & 7) << 4))) =
                    resid[ct * 16 + mt * 4 + r] + (ct ? b21 : b20);
            }
        }
    }
    __syncthreads();
    {
        for (int i = tid; i < 256 * 49; i += 512) {
            int c = i / 49, l = i - c * 49;
            int hh = wh * 7 + l / 7, ww = w7 * 7 + (l % 7);
            out[((size_t)(b * 256 + c) * 224 + hh) * 224 + ww] =
                *(const float*)(smem + l * 1024 + ((c * 4) ^ ((l & 7) << 4)));
        }
    }
}

extern "C" void kernel_launch(void* const* d_in, const int* in_sizes, int n_in,
                              void* d_out, int out_size, void* d_ws, size_t ws_size,
                              hipStream_t stream) {
    const float* x   = (const float*)d_in[0];
    const float* n1w = (const float*)d_in[1];
    const float* n1b = (const float*)d_in[2];
    const float* Wq  = (const float*)d_in[3];
    const float* Bq  = (const float*)d_in[4];
    const float* Wo  = (const float*)d_in[5];
    const float* Bo  = (const float*)d_in[6];
    const float* n2w = (const float*)d_in[7];
    const float* n2b = (const float*)d_in[8];
    const float* W1  = (const float*)d_in[9];
    const float* B1  = (const float*)d_in[10];
    const float* W2  = (const float*)d_in[11];
    const float* B2  = (const float*)d_in[12];
    float* out = (float*)d_out;
    (void)in_sizes; (void)n_in; (void)out_size; (void)ws_size;

    short* wsp = (short*)d_ws;
    short* WqB = wsp;                // 196608 shorts
    short* WoB = wsp + 196608;       // 65536
    short* W1B = wsp + 262144;       // 262144
    short* W2B = wsp + 524288;       // 262144   (total 1.57 MB)

    prep_kernel<<<192, 256, 0, stream>>>(Wq, WqB, 49152);
    prep_kernel<<<64,  256, 0, stream>>>(Wo, WoB, 16384);
    prep_kernel<<<256, 256, 0, stream>>>(W1, W1B, 65536);
    prep_kernel<<<256, 256, 0, stream>>>(W2, W2B, 65536);

    swin_kernel<<<8192, 512, 75264, stream>>>(x, n1w, n1b, WqB, Bq, WoB, Bo,
                                              n2w, n2b, W1B, B1, W2B, B2, out);
}

// Round 3
// 6391.685 us; speedup vs baseline: 1.1396x; 1.1396x over previous
//
#include <hip/hip_runtime.h>
#include <hip/hip_bf16.h>
#include <math.h>

#define DEVI __device__ __forceinline__
typedef __attribute__((ext_vector_type(8))) short bf16x8;
typedef __attribute__((ext_vector_type(4))) float f32x4;
typedef __attribute__((ext_vector_type(4))) short s16x4;

#define MFMA(a, b, c) __builtin_amdgcn_mfma_f32_16x16x32_bf16((a), (b), (c), 0, 0, 0)

DEVI short f2bf(float f) {
    unsigned u = __builtin_bit_cast(unsigned, f);
    return (short)((u + 0x7FFFu + ((u >> 16) & 1u)) >> 16);
}
DEVI float bf2f(short s) {
    unsigned u = ((unsigned)(unsigned short)s) << 16;
    return __builtin_bit_cast(float, u);
}
DEVI int swz(int row, int cb, int ld) { return row * ld + (cb ^ ((row & 7) << 4)); }

// fp32 -> bf16 weight pre-conversion (amortized across all 8192 blocks)
__global__ void prep_kernel(const float* __restrict__ s, short* __restrict__ d, int n4) {
    int i = blockIdx.x * 256 + threadIdx.x;
    if (i < n4) {
        f32x4 v = ((const f32x4*)s)[i];
        s16x4 o;
        o[0] = f2bf(v[0]); o[1] = f2bf(v[1]); o[2] = f2bf(v[2]); o[3] = f2bf(v[3]);
        ((s16x4*)d)[i] = o;
    }
}

// LDS map (76288 B -> 2 blocks/CU):
//  [0,50176)      sX fp32 (gather->LN1). Then: O bf16 [49r x 512B swz] @0;
//                 later y bf16 @0; CQ@25088 CK@31360 CV@37632 (satt overlays CQ/CK);
//                 later H (MLP chunk) @25088; finally fp32 staging [49 x 1024B swz] @0
//  [50176,75264)  SW bf16 [49r x 512B swz]: normed win -> in-place residual stream
//  [75264,76288)  LN stats (mean,rstd per row)
__global__ __launch_bounds__(512, 4) void swin_kernel(
    const float* __restrict__ x,
    const float* __restrict__ n1w, const float* __restrict__ n1b,
    const short* __restrict__ WqB, const float* __restrict__ Bq,
    const short* __restrict__ WoB, const float* __restrict__ Bo,
    const float* __restrict__ n2w, const float* __restrict__ n2b,
    const short* __restrict__ W1B, const float* __restrict__ B1,
    const short* __restrict__ W2B, const float* __restrict__ B2,
    float* __restrict__ out)
{
    extern __shared__ __align__(16) char smem[];
    constexpr int OB = 0, CQ = 25088, CK = 31360, CV = 37632, SW = 50176, ST = 75264;

    const int bid = blockIdx.x;
    const int b = bid >> 10, wh = (bid >> 5) & 31, w7 = bid & 31;
    const int tid = threadIdx.x, wv = tid >> 6, lane = tid & 63;
    const int lg = lane >> 4, l15 = lane & 15;
    const int c0 = wv * 32 + l15;
    const f32x4 z = {0.f, 0.f, 0.f, 0.f};

    // ---------------- gather window -> sX[c][49] fp32 @0 ----------------
    {
        float* sX = (float*)smem;
        const float* xb = x + (size_t)b * (256 * 224 * 224);
        for (int i = tid; i < 256 * 49; i += 512) {
            int c = i / 49, l = i - c * 49;
            int hh = wh * 7 + l / 7, ww = w7 * 7 + (l % 7);
            sX[i] = xb[((size_t)c * 224 + hh) * 224 + ww];
        }
    }
    __syncthreads();
    // ---------------- LN1 stats -> ST ----------------
    {
        const int l = tid >> 3, s = tid & 7;
        if (l < 49) {
            const float* sX = (const float*)smem;
            float sum = 0.f, sq = 0.f;
            for (int ii = 0; ii < 32; ++ii) {
                int c = s * 32 + ((ii + tid) & 31);
                float v = sX[c * 49 + l];
                sum += v; sq += v * v;
            }
#pragma unroll
            for (int m = 1; m < 8; m <<= 1) { sum += __shfl_xor(sum, m); sq += __shfl_xor(sq, m); }
            if (s == 0) {
                float mean = sum * (1.f / 256.f);
                ((float*)(smem + ST))[l * 2] = mean;
                ((float*)(smem + ST))[l * 2 + 1] = rsqrtf(sq * (1.f / 256.f) - mean * mean + 1e-5f);
            }
        }
    }
    __syncthreads();
    // ---------------- LN1 apply: sX -> SW bf16 (no region overlap) --------
    {
        const float* sX = (const float*)smem;
        const float* st = (const float*)(smem + ST);
        float w0 = n1w[c0], b0 = n1b[c0], w1 = n1w[c0 + 16], b1 = n1b[c0 + 16];
#pragma unroll
        for (int ct = 0; ct < 2; ++ct)
#pragma unroll
        for (int mt = 0; mt < 4; ++mt)
#pragma unroll
        for (int r = 0; r < 4; ++r) {
            int row = mt * 16 + lg * 4 + r, col = c0 + ct * 16;
            if (row < 49) {
                float v = (sX[col * 49 + row] - st[row * 2]) * st[row * 2 + 1] * (ct ? w1 : w0) + (ct ? b1 : b0);
                *(short*)(smem + SW + swz(row, col * 2, 512)) = f2bf(v);
            }
        }
    }
    __syncthreads();

    // ---------------- attention: 4 head-pair chunks ----------------
    const int grp = wv >> 2, mts = wv & 3;
    int arow = mts * 16 + l15; if (arow > 48) arow = 48;
#pragma unroll 1
    for (int hp = 0; hp < 4; ++hp) {
#pragma unroll 1
        for (int sub = 0; sub < 2; ++sub) {
            if (sub == 0 || wv < 4) {
                const int t = sub ? (8 + wv) : wv;
                const int part = t >> 2, tt = t & 3;
                const int lc = tt * 16 + l15;
                const int jw = part * 256 + hp * 64 + lc;
                f32x4 a0 = z, a1 = z, a2 = z, a3 = z;
                const short* wr = WqB + (size_t)jw * 256 + lg * 8;
#pragma unroll
                for (int kk = 0; kk < 8; ++kk) {
                    bf16x8 bw = *(const bf16x8*)(wr + kk * 32);
                    const int cb = kk * 64 + lg * 16;
                    bf16x8 f0 = *(const bf16x8*)(smem + SW + swz(l15, cb, 512));
                    bf16x8 f1 = *(const bf16x8*)(smem + SW + swz(16 + l15, cb, 512));
                    bf16x8 f2 = *(const bf16x8*)(smem + SW + swz(32 + l15, cb, 512));
                    bf16x8 f3 = *(const bf16x8*)(smem + SW + swz(48, cb, 512));
                    a0 = MFMA(f0, bw, a0); a1 = MFMA(f1, bw, a1);
                    a2 = MFMA(f2, bw, a2); a3 = MFMA(f3, bw, a3);
                }
                const float bias = Bq[jw];
                if (part < 2) {
                    char* base = smem + (part ? CK : CQ);
#pragma unroll
                    for (int mt = 0; mt < 4; ++mt) {
                        f32x4 av = (mt == 0) ? a0 : (mt == 1) ? a1 : (mt == 2) ? a2 : a3;
#pragma unroll
                        for (int r = 0; r < 4; ++r) {
                            int row = mt * 16 + lg * 4 + r;
                            if (row < 49) *(short*)(base + swz(row, lc * 2, 128)) = f2bf(av[r] + bias);
                        }
                    }
                } else {
#pragma unroll
                    for (int mt = 0; mt < 4; ++mt) {
                        f32x4 av = (mt == 0) ? a0 : (mt == 1) ? a1 : (mt == 2) ? a2 : a3;
#pragma unroll
                        for (int r = 0; r < 4; ++r) {
                            int row = mt * 16 + lg * 4 + r;
                            *(short*)(smem + CV + swz(lc, row * 2, 128)) = f2bf(av[r] + bias);
                        }
                    }
                }
            }
        }
        __syncthreads();
        // QK^T + softmax (in registers)
        const int hb = grp * 64 + lg * 16;
        f32x4 s0 = z, s1 = z, s2 = z, s3 = z;
        {
            bf16x8 qa = *(const bf16x8*)(smem + CQ + swz(arow, hb, 128));
            bf16x8 k0 = *(const bf16x8*)(smem + CK + swz(l15, hb, 128));
            bf16x8 k1 = *(const bf16x8*)(smem + CK + swz(16 + l15, hb, 128));
            bf16x8 k2 = *(const bf16x8*)(smem + CK + swz(32 + l15, hb, 128));
            bf16x8 k3 = *(const bf16x8*)(smem + CK + swz(48, hb, 128));
            s0 = MFMA(qa, k0, s0); s1 = MFMA(qa, k1, s1);
            s2 = MFMA(qa, k2, s2); s3 = MFMA(qa, k3, s3);
        }
        const float scale = 0.17677669529663687f;
        float pr[4][4];
#pragma unroll
        for (int rj = 0; rj < 4; ++rj) {
            float v0 = s0[rj] * scale, v1 = s1[rj] * scale;
            float v2 = s2[rj] * scale, v3 = s3[rj] * scale;
            const int c3 = 48 + l15;
            float mx = fmaxf(fmaxf(v0, v1), v2);
            if (c3 < 49) mx = fmaxf(mx, v3);
#pragma unroll
            for (int mm = 1; mm < 16; mm <<= 1) mx = fmaxf(mx, __shfl_xor(mx, mm));
            float e0 = __expf(v0 - mx), e1 = __expf(v1 - mx), e2 = __expf(v2 - mx);
            float e3 = (c3 < 49) ? __expf(v3 - mx) : 0.f;
            float sm = e0 + e1 + e2 + e3;
#pragma unroll
            for (int mm = 1; mm < 16; mm <<= 1) sm += __shfl_xor(sm, mm);
            float inv = 1.f / sm;
            pr[rj][0] = e0 * inv; pr[rj][1] = e1 * inv;
            pr[rj][2] = e2 * inv; pr[rj][3] = e3 * inv;
        }
        __syncthreads();    // q/k reads complete before satt overlays them
        char* satt = smem + CQ + grp * 6272;
#pragma unroll
        for (int rj = 0; rj < 4; ++rj) {
            int row = mts * 16 + lg * 4 + rj;
            if (row < 49) {
                *(short*)(satt + swz(row, l15 * 2, 128)) = f2bf(pr[rj][0]);
                *(short*)(satt + swz(row, (16 + l15) * 2, 128)) = f2bf(pr[rj][1]);
                *(short*)(satt + swz(row, (32 + l15) * 2, 128)) = f2bf(pr[rj][2]);
                *(short*)(satt + swz(row, (48 + l15) * 2, 128)) = f2bf(pr[rj][3]);
            }
        }
        __syncthreads();
        // PV -> O columns [hp*64 + grp*32 .. +32)
        f32x4 o0 = z, o1 = z;
#pragma unroll
        for (int kk = 0; kk < 2; ++kk) {
            const int kb = kk * 64 + lg * 16;
            bf16x8 pa  = *(const bf16x8*)(satt + swz(arow, kb, 128));
            bf16x8 vb0 = *(const bf16x8*)(smem + CV + swz(grp * 32 + l15, kb, 128));
            bf16x8 vb1 = *(const bf16x8*)(smem + CV + swz(grp * 32 + 16 + l15, kb, 128));
            o0 = MFMA(pa, vb0, o0); o1 = MFMA(pa, vb1, o1);
        }
#pragma unroll
        for (int nt = 0; nt < 2; ++nt) {
            f32x4 ov = nt ? o1 : o0;
#pragma unroll
            for (int r = 0; r < 4; ++r) {
                int row = mts * 16 + lg * 4 + r;
                if (row < 49) {
                    int col = hp * 64 + grp * 32 + nt * 16 + l15;
                    *(short*)(smem + OB + swz(row, col * 2, 512)) = f2bf(ov[r]);
                }
            }
        }
        __syncthreads();
    }

    // ---------------- out-proj + in-place residual update of SW -----------
#pragma unroll 1
    for (int ct = 0; ct < 2; ++ct) {
        const int j = c0 + ct * 16;
        f32x4 a0 = z, a1 = z, a2 = z, a3 = z;
        const short* wr = WoB + (size_t)j * 256 + lg * 8;
#pragma unroll
        for (int kk = 0; kk < 8; ++kk) {
            bf16x8 bw = *(const bf16x8*)(wr + kk * 32);
            const int cb = kk * 64 + lg * 16;
            bf16x8 f0 = *(const bf16x8*)(smem + OB + swz(l15, cb, 512));
            bf16x8 f1 = *(const bf16x8*)(smem + OB + swz(16 + l15, cb, 512));
            bf16x8 f2 = *(const bf16x8*)(smem + OB + swz(32 + l15, cb, 512));
            bf16x8 f3 = *(const bf16x8*)(smem + OB + swz(48, cb, 512));
            a0 = MFMA(f0, bw, a0); a1 = MFMA(f1, bw, a1);
            a2 = MFMA(f2, bw, a2); a3 = MFMA(f3, bw, a3);
        }
        const float bias = Bo[j];
#pragma unroll
        for (int mt = 0; mt < 4; ++mt) {
            f32x4 av = (mt == 0) ? a0 : (mt == 1) ? a1 : (mt == 2) ? a2 : a3;
#pragma unroll
            for (int r = 0; r < 4; ++r) {
                int row = mt * 16 + lg * 4 + r;
                if (row < 49) {
                    short* p = (short*)(smem + SW + swz(row, j * 2, 512));
                    *p = f2bf(bf2f(*p) + av[r] + bias);   // owner-exclusive address
                }
            }
        }
    }
    __syncthreads();
    // ---------------- LN2 stats from SW (bf16) -> ST ----------------------
    {
        const int l = tid >> 3, s = tid & 7;
        if (l < 49) {
            float sum = 0.f, sq = 0.f;
            for (int ii = 0; ii < 32; ++ii) {
                int c = s * 32 + ((ii + tid) & 31);
                float v = bf2f(*(const short*)(smem + SW + swz(l, c * 2, 512)));
                sum += v; sq += v * v;
            }
#pragma unroll
            for (int m = 1; m < 8; m <<= 1) { sum += __shfl_xor(sum, m); sq += __shfl_xor(sq, m); }
            if (s == 0) {
                float mean = sum * (1.f / 256.f);
                ((float*)(smem + ST))[l * 2] = mean;
                ((float*)(smem + ST))[l * 2 + 1] = rsqrtf(sq * (1.f / 256.f) - mean * mean + 1e-5f);
            }
        }
    }
    __syncthreads();
    // ---------------- LN2 apply: SW -> y bf16 @0 (O dead) -----------------
    {
        const float* st = (const float*)(smem + ST);
        float w0 = n2w[c0], b0 = n2b[c0], w1 = n2w[c0 + 16], b1 = n2b[c0 + 16];
#pragma unroll
        for (int ct = 0; ct < 2; ++ct)
#pragma unroll
        for (int mt = 0; mt < 4; ++mt)
#pragma unroll
        for (int r = 0; r < 4; ++r) {
            int row = mt * 16 + lg * 4 + r, col = c0 + ct * 16;
            if (row < 49) {
                float v = bf2f(*(const short*)(smem + SW + swz(row, col * 2, 512)));
                float yv = (v - st[row * 2]) * st[row * 2 + 1] * (ct ? w1 : w0) + (ct ? b1 : b0);
                *(short*)(smem + OB + swz(row, col * 2, 512)) = f2bf(yv);
            }
        }
    }
    __syncthreads();
    // ---------------- MLP: 4 hidden chunks of 256 ----------------
    f32x4 macc[8];
#pragma unroll
    for (int i = 0; i < 8; ++i) macc[i] = z;
#pragma unroll 1
    for (int chunk = 0; chunk < 4; ++chunk) {
#pragma unroll 1
        for (int ct = 0; ct < 2; ++ct) {
            const int lcol = c0 + ct * 16;
            const int jj = chunk * 256 + lcol;
            f32x4 a0 = z, a1 = z, a2 = z, a3 = z;
            const short* wr = W1B + (size_t)jj * 256 + lg * 8;
#pragma unroll
            for (int kk = 0; kk < 8; ++kk) {
                bf16x8 bw = *(const bf16x8*)(wr + kk * 32);
                const int cb = kk * 64 + lg * 16;
                bf16x8 f0 = *(const bf16x8*)(smem + OB + swz(l15, cb, 512));
                bf16x8 f1 = *(const bf16x8*)(smem + OB + swz(16 + l15, cb, 512));
                bf16x8 f2 = *(const bf16x8*)(smem + OB + swz(32 + l15, cb, 512));
                bf16x8 f3 = *(const bf16x8*)(smem + OB + swz(48, cb, 512));
                a0 = MFMA(f0, bw, a0); a1 = MFMA(f1, bw, a1);
                a2 = MFMA(f2, bw, a2); a3 = MFMA(f3, bw, a3);
            }
            const float bias = B1[jj];
#pragma unroll
            for (int mt = 0; mt < 4; ++mt) {
                f32x4 av = (mt == 0) ? a0 : (mt == 1) ? a1 : (mt == 2) ? a2 : a3;
#pragma unroll
                for (int r = 0; r < 4; ++r) {
                    int row = mt * 16 + lg * 4 + r;
                    if (row < 49) {
                        float v = av[r] + bias;
                        float g = 0.5f * v * (1.f + erff(v * 0.70710678118654752f));
                        *(short*)(smem + CQ + swz(row, lcol * 2, 512)) = f2bf(g);
                    }
                }
            }
        }
        __syncthreads();
#pragma unroll 1
        for (int ct = 0; ct < 2; ++ct) {
            const int j = c0 + ct * 16;
            const short* wr = W2B + (size_t)j * 1024 + chunk * 256 + lg * 8;
#pragma unroll
            for (int kk = 0; kk < 8; ++kk) {
                bf16x8 bw = *(const bf16x8*)(wr + kk * 32);
                const int cb = kk * 64 + lg * 16;
                bf16x8 f0 = *(const bf16x8*)(smem + CQ + swz(l15, cb, 512));
                bf16x8 f1 = *(const bf16x8*)(smem + CQ + swz(16 + l15, cb, 512));
                bf16x8 f2 = *(const bf16x8*)(smem + CQ + swz(32 + l15, cb, 512));
                bf16x8 f3 = *(const bf16x8*)(smem + CQ + swz(48, cb, 512));
                macc[ct * 4 + 0] = MFMA(f0, bw, macc[ct * 4 + 0]);
                macc[ct * 4 + 1] = MFMA(f1, bw, macc[ct * 4 + 1]);
                macc[ct * 4 + 2] = MFMA(f2, bw, macc[ct * 4 + 2]);
                macc[ct * 4 + 3] = MFMA(f3, bw, macc[ct * 4 + 3]);
            }
        }
        __syncthreads();
    }
    // ---------------- final: resid + mlp2 + b2 -> fp32 staging @0 ---------
    {
        float b20 = B2[c0], b21 = B2[c0 + 16];
#pragma unroll
        for (int ct = 0; ct < 2; ++ct)
#pragma unroll
        for (int mt = 0; mt < 4; ++mt)
#pragma unroll
        for (int r = 0; r < 4; ++r) {
            int row = mt * 16 + lg * 4 + r, col = c0 + ct * 16;
            if (row < 49) {
                float base = bf2f(*(const short*)(smem + SW + swz(row, col * 2, 512)));
                *(float*)(smem + row * 1024 + ((col * 4) ^ ((row & 7) << 4))) =
                    base + macc[ct * 4 + mt][r] + (ct ? b21 : b20);
            }
        }
    }
    __syncthreads();
    // ---------------- window-reverse scatter store ------------------------
    {
        for (int i = tid; i < 256 * 49; i += 512) {
            int c = i / 49, l = i - c * 49;
            int hh = wh * 7 + l / 7, ww = w7 * 7 + (l % 7);
            out[((size_t)(b * 256 + c) * 224 + hh) * 224 + ww] =
                *(const float*)(smem + l * 1024 + ((c * 4) ^ ((l & 7) << 4)));
        }
    }
}

extern "C" void kernel_launch(void* const* d_in, const int* in_sizes, int n_in,
                              void* d_out, int out_size, void* d_ws, size_t ws_size,
                              hipStream_t stream) {
    const float* x   = (const float*)d_in[0];
    const float* n1w = (const float*)d_in[1];
    const float* n1b = (const float*)d_in[2];
    const float* Wq  = (const float*)d_in[3];
    const float* Bq  = (const float*)d_in[4];
    const float* Wo  = (const float*)d_in[5];
    const float* Bo  = (const float*)d_in[6];
    const float* n2w = (const float*)d_in[7];
    const float* n2b = (const float*)d_in[8];
    const float* W1  = (const float*)d_in[9];
    const float* B1  = (const float*)d_in[10];
    const float* W2  = (const float*)d_in[11];
    const float* B2  = (const float*)d_in[12];
    float* out = (float*)d_out;
    (void)in_sizes; (void)n_in; (void)out_size; (void)ws_size;

    short* wsp = (short*)d_ws;
    short* WqB = wsp;                // 196608 shorts
    short* WoB = wsp + 196608;       // 65536
    short* W1B = wsp + 262144;       // 262144
    short* W2B = wsp + 524288;       // 262144   (total 1.57 MB)

    prep_kernel<<<192, 256, 0, stream>>>(Wq, WqB, 49152);
    prep_kernel<<<64,  256, 0, stream>>>(Wo, WoB, 16384);
    prep_kernel<<<256, 256, 0, stream>>>(W1, W1B, 65536);
    prep_kernel<<<256, 256, 0, stream>>>(W2, W2B, 65536);

    swin_kernel<<<8192, 512, 76288, stream>>>(x, n1w, n1b, WqB, Bq, WoB, Bo,
                                              n2w, n2b, W1B, B1, W2B, B2, out);
}

// Round 4
// 2489.331 us; speedup vs baseline: 2.9261x; 2.5676x over previous
//
#include <hip/hip_runtime.h>
#include <hip/hip_bf16.h>
#include <math.h>

#define DEVI __device__ __forceinline__
typedef __attribute__((ext_vector_type(8))) short bf16x8;
typedef __attribute__((ext_vector_type(4))) float f32x4;
typedef __attribute__((ext_vector_type(4))) short s16x4;

#define MFMA(a, b, c) __builtin_amdgcn_mfma_f32_16x16x32_bf16((a), (b), (c), 0, 0, 0)

DEVI short f2bf(float f) {
    unsigned u = __builtin_bit_cast(unsigned, f);
    return (short)((u + 0x7FFFu + ((u >> 16) & 1u)) >> 16);
}
DEVI float bf2f(short s) {
    unsigned u = ((unsigned)(unsigned short)s) << 16;
    return __builtin_bit_cast(float, u);
}
DEVI int swz(int row, int cb, int ld) { return row * ld + (cb ^ ((row & 7) << 4)); }

// fp32 -> bf16 weight pre-conversion
__global__ void prep_kernel(const float* __restrict__ s, short* __restrict__ d, int n4) {
    int i = blockIdx.x * 256 + threadIdx.x;
    if (i < n4) {
        f32x4 v = ((const f32x4*)s)[i];
        s16x4 o;
        o[0] = f2bf(v[0]); o[1] = f2bf(v[1]); o[2] = f2bf(v[2]); o[3] = f2bf(v[3]);
        ((s16x4*)d)[i] = o;
    }
}

// ============================================================================
// KA: gather -> LN1 -> QKV -> attention -> out-proj + residual -> R (bf16, ws)
// ============================================================================
__global__ __launch_bounds__(512, 4) void swin_attn(
    const float* __restrict__ x,
    const float* __restrict__ n1w, const float* __restrict__ n1b,
    const short* __restrict__ WqB, const float* __restrict__ Bq,
    const short* __restrict__ WoB, const float* __restrict__ Bo,
    short* __restrict__ Rws)
{
    extern __shared__ __align__(16) char smem[];
    constexpr int OB = 0, CQ = 25088, CK = 31360, CV = 37632, SW = 50176, ST = 75264;

    const int bid = blockIdx.x;
    const int b = bid >> 10, wh = (bid >> 5) & 31, w7 = bid & 31;
    const int tid = threadIdx.x, wv = tid >> 6, lane = tid & 63;
    const int lg = lane >> 4, l15 = lane & 15;
    const int c0 = wv * 32 + l15;
    const f32x4 z = {0.f, 0.f, 0.f, 0.f};

    // gather window -> sX[c][49] fp32 @0
    {
        float* sX = (float*)smem;
        const float* xb = x + (size_t)b * (256 * 224 * 224);
        for (int i = tid; i < 256 * 49; i += 512) {
            int c = i / 49, l = i - c * 49;
            int hh = wh * 7 + l / 7, ww = w7 * 7 + (l % 7);
            sX[i] = xb[((size_t)c * 224 + hh) * 224 + ww];
        }
    }
    __syncthreads();
    // LN1 stats
    {
        const int l = tid >> 3, s = tid & 7;
        if (l < 49) {
            const float* sX = (const float*)smem;
            float sum = 0.f, sq = 0.f;
            for (int ii = 0; ii < 32; ++ii) {
                int c = s * 32 + ((ii + tid) & 31);
                float v = sX[c * 49 + l];
                sum += v; sq += v * v;
            }
#pragma unroll
            for (int m = 1; m < 8; m <<= 1) { sum += __shfl_xor(sum, m); sq += __shfl_xor(sq, m); }
            if (s == 0) {
                float mean = sum * (1.f / 256.f);
                ((float*)(smem + ST))[l * 2] = mean;
                ((float*)(smem + ST))[l * 2 + 1] = rsqrtf(sq * (1.f / 256.f) - mean * mean + 1e-5f);
            }
        }
    }
    __syncthreads();
    // LN1 apply -> SW bf16
    {
        const float* sX = (const float*)smem;
        const float* st = (const float*)(smem + ST);
        float w0 = n1w[c0], b0 = n1b[c0], w1 = n1w[c0 + 16], b1 = n1b[c0 + 16];
#pragma unroll
        for (int ct = 0; ct < 2; ++ct)
#pragma unroll
        for (int mt = 0; mt < 4; ++mt)
#pragma unroll
        for (int r = 0; r < 4; ++r) {
            int row = mt * 16 + lg * 4 + r, col = c0 + ct * 16;
            if (row < 49) {
                float v = (sX[col * 49 + row] - st[row * 2]) * st[row * 2 + 1] * (ct ? w1 : w0) + (ct ? b1 : b0);
                *(short*)(smem + SW + swz(row, col * 2, 512)) = f2bf(v);
            }
        }
    }
    __syncthreads();

    // attention: 4 head-pair chunks
    const int grp = wv >> 2, mts = wv & 3;
    int arow = mts * 16 + l15; if (arow > 48) arow = 48;
#pragma unroll 1
    for (int hp = 0; hp < 4; ++hp) {
#pragma unroll 1
        for (int sub = 0; sub < 2; ++sub) {
            if (sub == 0 || wv < 4) {
                const int t = sub ? (8 + wv) : wv;
                const int part = t >> 2, tt = t & 3;
                const int lc = tt * 16 + l15;
                const int jw = part * 256 + hp * 64 + lc;
                f32x4 a0 = z, a1 = z, a2 = z, a3 = z;
                const short* wr = WqB + (size_t)jw * 256 + lg * 8;
#pragma unroll
                for (int kk = 0; kk < 8; ++kk) {
                    bf16x8 bw = *(const bf16x8*)(wr + kk * 32);
                    const int cb = kk * 64 + lg * 16;
                    bf16x8 f0 = *(const bf16x8*)(smem + SW + swz(l15, cb, 512));
                    bf16x8 f1 = *(const bf16x8*)(smem + SW + swz(16 + l15, cb, 512));
                    bf16x8 f2 = *(const bf16x8*)(smem + SW + swz(32 + l15, cb, 512));
                    bf16x8 f3 = *(const bf16x8*)(smem + SW + swz(48, cb, 512));
                    a0 = MFMA(f0, bw, a0); a1 = MFMA(f1, bw, a1);
                    a2 = MFMA(f2, bw, a2); a3 = MFMA(f3, bw, a3);
                }
                const float bias = Bq[jw];
                if (part < 2) {
                    char* base = smem + (part ? CK : CQ);
#pragma unroll
                    for (int mt = 0; mt < 4; ++mt) {
                        f32x4 av = (mt == 0) ? a0 : (mt == 1) ? a1 : (mt == 2) ? a2 : a3;
#pragma unroll
                        for (int r = 0; r < 4; ++r) {
                            int row = mt * 16 + lg * 4 + r;
                            if (row < 49) *(short*)(base + swz(row, lc * 2, 128)) = f2bf(av[r] + bias);
                        }
                    }
                } else {
#pragma unroll
                    for (int mt = 0; mt < 4; ++mt) {
                        f32x4 av = (mt == 0) ? a0 : (mt == 1) ? a1 : (mt == 2) ? a2 : a3;
#pragma unroll
                        for (int r = 0; r < 4; ++r) {
                            int row = mt * 16 + lg * 4 + r;
                            *(short*)(smem + CV + swz(lc, row * 2, 128)) = f2bf(av[r] + bias);
                        }
                    }
                }
            }
        }
        __syncthreads();
        const int hb = grp * 64 + lg * 16;
        f32x4 s0 = z, s1 = z, s2 = z, s3 = z;
        {
            bf16x8 qa = *(const bf16x8*)(smem + CQ + swz(arow, hb, 128));
            bf16x8 k0 = *(const bf16x8*)(smem + CK + swz(l15, hb, 128));
            bf16x8 k1 = *(const bf16x8*)(smem + CK + swz(16 + l15, hb, 128));
            bf16x8 k2 = *(const bf16x8*)(smem + CK + swz(32 + l15, hb, 128));
            bf16x8 k3 = *(const bf16x8*)(smem + CK + swz(48, hb, 128));
            s0 = MFMA(qa, k0, s0); s1 = MFMA(qa, k1, s1);
            s2 = MFMA(qa, k2, s2); s3 = MFMA(qa, k3, s3);
        }
        const float scale = 0.17677669529663687f;
        float pr[4][4];
#pragma unroll
        for (int rj = 0; rj < 4; ++rj) {
            float v0 = s0[rj] * scale, v1 = s1[rj] * scale;
            float v2 = s2[rj] * scale, v3 = s3[rj] * scale;
            const int c3 = 48 + l15;
            float mx = fmaxf(fmaxf(v0, v1), v2);
            if (c3 < 49) mx = fmaxf(mx, v3);
#pragma unroll
            for (int mm = 1; mm < 16; mm <<= 1) mx = fmaxf(mx, __shfl_xor(mx, mm));
            float e0 = __expf(v0 - mx), e1 = __expf(v1 - mx), e2 = __expf(v2 - mx);
            float e3 = (c3 < 49) ? __expf(v3 - mx) : 0.f;
            float sm = e0 + e1 + e2 + e3;
#pragma unroll
            for (int mm = 1; mm < 16; mm <<= 1) sm += __shfl_xor(sm, mm);
            float inv = 1.f / sm;
            pr[rj][0] = e0 * inv; pr[rj][1] = e1 * inv;
            pr[rj][2] = e2 * inv; pr[rj][3] = e3 * inv;
        }
        __syncthreads();
        char* satt = smem + CQ + grp * 6272;
#pragma unroll
        for (int rj = 0; rj < 4; ++rj) {
            int row = mts * 16 + lg * 4 + rj;
            if (row < 49) {
                *(short*)(satt + swz(row, l15 * 2, 128)) = f2bf(pr[rj][0]);
                *(short*)(satt + swz(row, (16 + l15) * 2, 128)) = f2bf(pr[rj][1]);
                *(short*)(satt + swz(row, (32 + l15) * 2, 128)) = f2bf(pr[rj][2]);
                *(short*)(satt + swz(row, (48 + l15) * 2, 128)) = f2bf(pr[rj][3]);
            }
        }
        __syncthreads();
        f32x4 o0 = z, o1 = z;
#pragma unroll
        for (int kk = 0; kk < 2; ++kk) {
            const int kb = kk * 64 + lg * 16;
            bf16x8 pa  = *(const bf16x8*)(satt + swz(arow, kb, 128));
            bf16x8 vb0 = *(const bf16x8*)(smem + CV + swz(grp * 32 + l15, kb, 128));
            bf16x8 vb1 = *(const bf16x8*)(smem + CV + swz(grp * 32 + 16 + l15, kb, 128));
            o0 = MFMA(pa, vb0, o0); o1 = MFMA(pa, vb1, o1);
        }
#pragma unroll
        for (int nt = 0; nt < 2; ++nt) {
            f32x4 ov = nt ? o1 : o0;
#pragma unroll
            for (int r = 0; r < 4; ++r) {
                int row = mts * 16 + lg * 4 + r;
                if (row < 49) {
                    int col = hp * 64 + grp * 32 + nt * 16 + l15;
                    *(short*)(smem + OB + swz(row, col * 2, 512)) = f2bf(ov[r]);
                }
            }
        }
        __syncthreads();
    }

    // out-proj + in-place residual update of SW
#pragma unroll 1
    for (int ct = 0; ct < 2; ++ct) {
        const int j = c0 + ct * 16;
        f32x4 a0 = z, a1 = z, a2 = z, a3 = z;
        const short* wr = WoB + (size_t)j * 256 + lg * 8;
#pragma unroll
        for (int kk = 0; kk < 8; ++kk) {
            bf16x8 bw = *(const bf16x8*)(wr + kk * 32);
            const int cb = kk * 64 + lg * 16;
            bf16x8 f0 = *(const bf16x8*)(smem + OB + swz(l15, cb, 512));
            bf16x8 f1 = *(const bf16x8*)(smem + OB + swz(16 + l15, cb, 512));
            bf16x8 f2 = *(const bf16x8*)(smem + OB + swz(32 + l15, cb, 512));
            bf16x8 f3 = *(const bf16x8*)(smem + OB + swz(48, cb, 512));
            a0 = MFMA(f0, bw, a0); a1 = MFMA(f1, bw, a1);
            a2 = MFMA(f2, bw, a2); a3 = MFMA(f3, bw, a3);
        }
        const float bias = Bo[j];
#pragma unroll
        for (int mt = 0; mt < 4; ++mt) {
            f32x4 av = (mt == 0) ? a0 : (mt == 1) ? a1 : (mt == 2) ? a2 : a3;
#pragma unroll
            for (int r = 0; r < 4; ++r) {
                int row = mt * 16 + lg * 4 + r;
                if (row < 49) {
                    short* p = (short*)(smem + SW + swz(row, j * 2, 512));
                    *p = f2bf(bf2f(*p) + av[r] + bias);
                }
            }
        }
    }
    __syncthreads();
    // write R rows (token-major, coalesced)
    {
        for (int i = tid; i < 49 * 32; i += 512) {
            int row = i >> 5, c8 = (i & 31) * 8;
            bf16x8 v = *(const bf16x8*)(smem + SW + swz(row, c8 * 2, 512));
            *(bf16x8*)(Rws + ((size_t)bid * 49 + row) * 256 + c8) = v;
        }
    }
}

// ============================================================================
// KB: fused MLP over dense token rows. tile = 128 rows x 256 cols, K=256.
// LDS: Z @0 (64K), H @65536 (64K), stats @131072, n2w/n2b @132096/133120.
// Epilogue fp32 staging [64][257] overlays Z/H (dead).
// ============================================================================
__global__ __launch_bounds__(512, 1) void mlp_kernel(
    const short* __restrict__ Rws,
    const float* __restrict__ n2w, const float* __restrict__ n2b,
    const short* __restrict__ W1B, const float* __restrict__ B1,
    const short* __restrict__ W2B, const float* __restrict__ B2,
    float* __restrict__ out)
{
    extern __shared__ __align__(16) char smem[];
    constexpr int HB = 65536, STT = 131072, NW = 132096, NB = 133120;
    const int tile = blockIdx.x;
    const int tid = threadIdx.x, wv = tid >> 6, lane = tid & 63;
    const int lg = lane >> 4, l15 = lane & 15;
    const int wm = wv >> 2, wn = wv & 3;
    const f32x4 z = {0.f, 0.f, 0.f, 0.f};

    if (tid < 256) {
        ((float*)(smem + NW))[tid] = n2w[tid];
        ((float*)(smem + NB))[tid] = n2b[tid];
    }
    // stage R tile -> LDS (bf16, swizzled)
#pragma unroll
    for (int it = 0; it < 8; ++it) {
        int e = it * 4096 + tid * 8;
        int row = e >> 8, c = e & 255;
        bf16x8 v = *(const bf16x8*)(Rws + ((size_t)tile * 128 + row) * 256 + c);
        *(bf16x8*)(smem + swz(row, c * 2, 512)) = v;
    }
    __syncthreads();
    // per-row LN2 stats (4 threads/row)
    {
        const int row = tid >> 2, sub = tid & 3;
        float sum = 0.f, sq = 0.f;
#pragma unroll
        for (int ii = 0; ii < 8; ++ii) {
            bf16x8 v = *(const bf16x8*)(smem + swz(row, (sub * 64 + ii * 8) * 2, 512));
#pragma unroll
            for (int j = 0; j < 8; ++j) { float f = bf2f(v[j]); sum += f; sq += f * f; }
        }
        sum += __shfl_xor(sum, 1); sq += __shfl_xor(sq, 1);
        sum += __shfl_xor(sum, 2); sq += __shfl_xor(sq, 2);
        if (sub == 0) {
            float mean = sum * (1.f / 256.f);
            ((float*)(smem + STT))[row * 2] = mean;
            ((float*)(smem + STT))[row * 2 + 1] = rsqrtf(sq * (1.f / 256.f) - mean * mean + 1e-5f);
        }
    }
    __syncthreads();
    // normalize in place -> Z
    {
        const int row = tid >> 2, sub = tid & 3;
        float m = ((const float*)(smem + STT))[row * 2];
        float rs = ((const float*)(smem + STT))[row * 2 + 1];
        const float* nw = (const float*)(smem + NW);
        const float* nb = (const float*)(smem + NB);
#pragma unroll
        for (int ii = 0; ii < 8; ++ii) {
            char* p = smem + swz(row, (sub * 64 + ii * 8) * 2, 512);
            bf16x8 v = *(const bf16x8*)p;
            bf16x8 o;
#pragma unroll
            for (int j = 0; j < 8; ++j) {
                int c = sub * 64 + ii * 8 + j;
                o[j] = f2bf((bf2f(v[j]) - m) * rs * nw[c] + nb[c]);
            }
            *(bf16x8*)p = o;
        }
    }
    __syncthreads();

    f32x4 macc[16];
#pragma unroll
    for (int i = 0; i < 16; ++i) macc[i] = z;

#pragma unroll 1
    for (int chunk = 0; chunk < 4; ++chunk) {
        // GEMM1: H[128][256] = Z @ W1chunk^T  (reads Z only)
        f32x4 g1[16];
#pragma unroll
        for (int i = 0; i < 16; ++i) g1[i] = z;
#pragma unroll
        for (int kk = 0; kk < 8; ++kk) {
            const int cb = kk * 64 + lg * 16;
            bf16x8 a0 = *(const bf16x8*)(smem + swz(wm * 64 + l15, cb, 512));
            bf16x8 a1 = *(const bf16x8*)(smem + swz(wm * 64 + 16 + l15, cb, 512));
            bf16x8 a2 = *(const bf16x8*)(smem + swz(wm * 64 + 32 + l15, cb, 512));
            bf16x8 a3 = *(const bf16x8*)(smem + swz(wm * 64 + 48 + l15, cb, 512));
#pragma unroll
            for (int nf = 0; nf < 4; ++nf) {
                const int j = chunk * 256 + wn * 64 + nf * 16 + l15;
                bf16x8 bw = *(const bf16x8*)(W1B + (size_t)j * 256 + kk * 32 + lg * 8);
                g1[0 * 4 + nf] = MFMA(a0, bw, g1[0 * 4 + nf]);
                g1[1 * 4 + nf] = MFMA(a1, bw, g1[1 * 4 + nf]);
                g1[2 * 4 + nf] = MFMA(a2, bw, g1[2 * 4 + nf]);
                g1[3 * 4 + nf] = MFMA(a3, bw, g1[3 * 4 + nf]);
            }
        }
        __syncthreads();   // prev GEMM2's H reads done
        // GELU + store H
#pragma unroll
        for (int mf = 0; mf < 4; ++mf)
#pragma unroll
        for (int nf = 0; nf < 4; ++nf) {
            const int hc = wn * 64 + nf * 16 + l15;
            const float bias = B1[chunk * 256 + hc];
#pragma unroll
            for (int r = 0; r < 4; ++r) {
                int row = wm * 64 + mf * 16 + lg * 4 + r;
                float v = g1[mf * 4 + nf][r] + bias;
                float g = 0.5f * v * (1.f + erff(v * 0.70710678118654752f));
                *(short*)(smem + HB + swz(row, hc * 2, 512)) = f2bf(g);
            }
        }
        __syncthreads();
        // GEMM2: accumulate out[128][256] += H @ W2chunk^T
#pragma unroll
        for (int kk = 0; kk < 8; ++kk) {
            const int cb = kk * 64 + lg * 16;
            bf16x8 a0 = *(const bf16x8*)(smem + HB + swz(wm * 64 + l15, cb, 512));
            bf16x8 a1 = *(const bf16x8*)(smem + HB + swz(wm * 64 + 16 + l15, cb, 512));
            bf16x8 a2 = *(const bf16x8*)(smem + HB + swz(wm * 64 + 32 + l15, cb, 512));
            bf16x8 a3 = *(const bf16x8*)(smem + HB + swz(wm * 64 + 48 + l15, cb, 512));
#pragma unroll
            for (int nf = 0; nf < 4; ++nf) {
                const int j = wn * 64 + nf * 16 + l15;
                bf16x8 bw = *(const bf16x8*)(W2B + (size_t)j * 1024 + chunk * 256 + kk * 32 + lg * 8);
                macc[0 * 4 + nf] = MFMA(a0, bw, macc[0 * 4 + nf]);
                macc[1 * 4 + nf] = MFMA(a1, bw, macc[1 * 4 + nf]);
                macc[2 * 4 + nf] = MFMA(a2, bw, macc[2 * 4 + nf]);
                macc[3 * 4 + nf] = MFMA(a3, bw, macc[3 * 4 + nf]);
            }
        }
    }
    // epilogue: two 64-row half-tiles, fp32 staging + window-reverse scatter
#pragma unroll 1
    for (int half = 0; half < 2; ++half) {
        __syncthreads();
        if (wm == half) {
            float* stg = (float*)smem;
#pragma unroll
            for (int mf = 0; mf < 4; ++mf)
#pragma unroll
            for (int nf = 0; nf < 4; ++nf) {
                const int c = wn * 64 + nf * 16 + l15;
                const float b2v = B2[c];
#pragma unroll
                for (int r = 0; r < 4; ++r) {
                    int rl = mf * 16 + lg * 4 + r;
                    size_t t = (size_t)tile * 128 + half * 64 + rl;
                    float rv = bf2f(Rws[t * 256 + c]);
                    stg[rl * 257 + c] = rv + macc[mf * 4 + nf][r] + b2v;
                }
            }
        }
        __syncthreads();
        const float* stg = (const float*)smem;
        for (int i = tid; i < 64 * 256; i += 512) {
            int c = i >> 6, rl = i & 63;
            int t = tile * 128 + half * 64 + rl;
            int win = t / 49, l = t - win * 49;
            int b = win >> 10, wh = (win >> 5) & 31, w7 = win & 31;
            out[((size_t)(b * 256 + c) * 224 + wh * 7 + l / 7) * 224 + w7 * 7 + (l % 7)] =
                stg[rl * 257 + c];
        }
    }
}

// ============================================================================
// Fallback monolith (round-3 kernel, proven correct) for small ws_size
// ============================================================================
__global__ __launch_bounds__(512, 4) void swin_mono(
    const float* __restrict__ x,
    const float* __restrict__ n1w, const float* __restrict__ n1b,
    const short* __restrict__ WqB, const float* __restrict__ Bq,
    const short* __restrict__ WoB, const float* __restrict__ Bo,
    const float* __restrict__ n2w, const float* __restrict__ n2b,
    const short* __restrict__ W1B, const float* __restrict__ B1,
    const short* __restrict__ W2B, const float* __restrict__ B2,
    float* __restrict__ out)
{
    extern __shared__ __align__(16) char smem[];
    constexpr int OB = 0, CQ = 25088, CK = 31360, CV = 37632, SW = 50176, ST = 75264;
    const int bid = blockIdx.x;
    const int b = bid >> 10, wh = (bid >> 5) & 31, w7 = bid & 31;
    const int tid = threadIdx.x, wv = tid >> 6, lane = tid & 63;
    const int lg = lane >> 4, l15 = lane & 15;
    const int c0 = wv * 32 + l15;
    const f32x4 z = {0.f, 0.f, 0.f, 0.f};
    {
        float* sX = (float*)smem;
        const float* xb = x + (size_t)b * (256 * 224 * 224);
        for (int i = tid; i < 256 * 49; i += 512) {
            int c = i / 49, l = i - c * 49;
            int hh = wh * 7 + l / 7, ww = w7 * 7 + (l % 7);
            sX[i] = xb[((size_t)c * 224 + hh) * 224 + ww];
        }
    }
    __syncthreads();
    {
        const int l = tid >> 3, s = tid & 7;
        if (l < 49) {
            const float* sX = (const float*)smem;
            float sum = 0.f, sq = 0.f;
            for (int ii = 0; ii < 32; ++ii) {
                int c = s * 32 + ((ii + tid) & 31);
                float v = sX[c * 49 + l];
                sum += v; sq += v * v;
            }
#pragma unroll
            for (int m = 1; m < 8; m <<= 1) { sum += __shfl_xor(sum, m); sq += __shfl_xor(sq, m); }
            if (s == 0) {
                float mean = sum * (1.f / 256.f);
                ((float*)(smem + ST))[l * 2] = mean;
                ((float*)(smem + ST))[l * 2 + 1] = rsqrtf(sq * (1.f / 256.f) - mean * mean + 1e-5f);
            }
        }
    }
    __syncthreads();
    {
        const float* sX = (const float*)smem;
        const float* st = (const float*)(smem + ST);
        float w0 = n1w[c0], b0 = n1b[c0], w1 = n1w[c0 + 16], b1 = n1b[c0 + 16];
#pragma unroll
        for (int ct = 0; ct < 2; ++ct)
#pragma unroll
        for (int mt = 0; mt < 4; ++mt)
#pragma unroll
        for (int r = 0; r < 4; ++r) {
            int row = mt * 16 + lg * 4 + r, col = c0 + ct * 16;
            if (row < 49) {
                float v = (sX[col * 49 + row] - st[row * 2]) * st[row * 2 + 1] * (ct ? w1 : w0) + (ct ? b1 : b0);
                *(short*)(smem + SW + swz(row, col * 2, 512)) = f2bf(v);
            }
        }
    }
    __syncthreads();
    const int grp = wv >> 2, mts = wv & 3;
    int arow = mts * 16 + l15; if (arow > 48) arow = 48;
#pragma unroll 1
    for (int hp = 0; hp < 4; ++hp) {
#pragma unroll 1
        for (int sub = 0; sub < 2; ++sub) {
            if (sub == 0 || wv < 4) {
                const int t = sub ? (8 + wv) : wv;
                const int part = t >> 2, tt = t & 3;
                const int lc = tt * 16 + l15;
                const int jw = part * 256 + hp * 64 + lc;
                f32x4 a0 = z, a1 = z, a2 = z, a3 = z;
                const short* wr = WqB + (size_t)jw * 256 + lg * 8;
#pragma unroll
                for (int kk = 0; kk < 8; ++kk) {
                    bf16x8 bw = *(const bf16x8*)(wr + kk * 32);
                    const int cb = kk * 64 + lg * 16;
                    bf16x8 f0 = *(const bf16x8*)(smem + SW + swz(l15, cb, 512));
                    bf16x8 f1 = *(const bf16x8*)(smem + SW + swz(16 + l15, cb, 512));
                    bf16x8 f2 = *(const bf16x8*)(smem + SW + swz(32 + l15, cb, 512));
                    bf16x8 f3 = *(const bf16x8*)(smem + SW + swz(48, cb, 512));
                    a0 = MFMA(f0, bw, a0); a1 = MFMA(f1, bw, a1);
                    a2 = MFMA(f2, bw, a2); a3 = MFMA(f3, bw, a3);
                }
                const float bias = Bq[jw];
                if (part < 2) {
                    char* base = smem + (part ? CK : CQ);
#pragma unroll
                    for (int mt = 0; mt < 4; ++mt) {
                        f32x4 av = (mt == 0) ? a0 : (mt == 1) ? a1 : (mt == 2) ? a2 : a3;
#pragma unroll
                        for (int r = 0; r < 4; ++r) {
                            int row = mt * 16 + lg * 4 + r;
                            if (row < 49) *(short*)(base + swz(row, lc * 2, 128)) = f2bf(av[r] + bias);
                        }
                    }
                } else {
#pragma unroll
                    for (int mt = 0; mt < 4; ++mt) {
                        f32x4 av = (mt == 0) ? a0 : (mt == 1) ? a1 : (mt == 2) ? a2 : a3;
#pragma unroll
                        for (int r = 0; r < 4; ++r) {
                            int row = mt * 16 + lg * 4 + r;
                            *(short*)(smem + CV + swz(lc, row * 2, 128)) = f2bf(av[r] + bias);
                        }
                    }
                }
            }
        }
        __syncthreads();
        const int hb = grp * 64 + lg * 16;
        f32x4 s0 = z, s1 = z, s2 = z, s3 = z;
        {
            bf16x8 qa = *(const bf16x8*)(smem + CQ + swz(arow, hb, 128));
            bf16x8 k0 = *(const bf16x8*)(smem + CK + swz(l15, hb, 128));
            bf16x8 k1 = *(const bf16x8*)(smem + CK + swz(16 + l15, hb, 128));
            bf16x8 k2 = *(const bf16x8*)(smem + CK + swz(32 + l15, hb, 128));
            bf16x8 k3 = *(const bf16x8*)(smem + CK + swz(48, hb, 128));
            s0 = MFMA(qa, k0, s0); s1 = MFMA(qa, k1, s1);
            s2 = MFMA(qa, k2, s2); s3 = MFMA(qa, k3, s3);
        }
        const float scale = 0.17677669529663687f;
        float pr[4][4];
#pragma unroll
        for (int rj = 0; rj < 4; ++rj) {
            float v0 = s0[rj] * scale, v1 = s1[rj] * scale;
            float v2 = s2[rj] * scale, v3 = s3[rj] * scale;
            const int c3 = 48 + l15;
            float mx = fmaxf(fmaxf(v0, v1), v2);
            if (c3 < 49) mx = fmaxf(mx, v3);
#pragma unroll
            for (int mm = 1; mm < 16; mm <<= 1) mx = fmaxf(mx, __shfl_xor(mx, mm));
            float e0 = __expf(v0 - mx), e1 = __expf(v1 - mx), e2 = __expf(v2 - mx);
            float e3 = (c3 < 49) ? __expf(v3 - mx) : 0.f;
            float sm = e0 + e1 + e2 + e3;
#pragma unroll
            for (int mm = 1; mm < 16; mm <<= 1) sm += __shfl_xor(sm, mm);
            float inv = 1.f / sm;
            pr[rj][0] = e0 * inv; pr[rj][1] = e1 * inv;
            pr[rj][2] = e2 * inv; pr[rj][3] = e3 * inv;
        }
        __syncthreads();
        char* satt = smem + CQ + grp * 6272;
#pragma unroll
        for (int rj = 0; rj < 4; ++rj) {
            int row = mts * 16 + lg * 4 + rj;
            if (row < 49) {
                *(short*)(satt + swz(row, l15 * 2, 128)) = f2bf(pr[rj][0]);
                *(short*)(satt + swz(row, (16 + l15) * 2, 128)) = f2bf(pr[rj][1]);
                *(short*)(satt + swz(row, (32 + l15) * 2, 128)) = f2bf(pr[rj][2]);
                *(short*)(satt + swz(row, (48 + l15) * 2, 128)) = f2bf(pr[rj][3]);
            }
        }
        __syncthreads();
        f32x4 o0 = z, o1 = z;
#pragma unroll
        for (int kk = 0; kk < 2; ++kk) {
            const int kb = kk * 64 + lg * 16;
            bf16x8 pa  = *(const bf16x8*)(satt + swz(arow, kb, 128));
            bf16x8 vb0 = *(const bf16x8*)(smem + CV + swz(grp * 32 + l15, kb, 128));
            bf16x8 vb1 = *(const bf16x8*)(smem + CV + swz(grp * 32 + 16 + l15, kb, 128));
            o0 = MFMA(pa, vb0, o0); o1 = MFMA(pa, vb1, o1);
        }
#pragma unroll
        for (int nt = 0; nt < 2; ++nt) {
            f32x4 ov = nt ? o1 : o0;
#pragma unroll
            for (int r = 0; r < 4; ++r) {
                int row = mts * 16 + lg * 4 + r;
                if (row < 49) {
                    int col = hp * 64 + grp * 32 + nt * 16 + l15;
                    *(short*)(smem + OB + swz(row, col * 2, 512)) = f2bf(ov[r]);
                }
            }
        }
        __syncthreads();
    }
#pragma unroll 1
    for (int ct = 0; ct < 2; ++ct) {
        const int j = c0 + ct * 16;
        f32x4 a0 = z, a1 = z, a2 = z, a3 = z;
        const short* wr = WoB + (size_t)j * 256 + lg * 8;
#pragma unroll
        for (int kk = 0; kk < 8; ++kk) {
            bf16x8 bw = *(const bf16x8*)(wr + kk * 32);
            const int cb = kk * 64 + lg * 16;
            bf16x8 f0 = *(const bf16x8*)(smem + OB + swz(l15, cb, 512));
            bf16x8 f1 = *(const bf16x8*)(smem + OB + swz(16 + l15, cb, 512));
            bf16x8 f2 = *(const bf16x8*)(smem + OB + swz(32 + l15, cb, 512));
            bf16x8 f3 = *(const bf16x8*)(smem + OB + swz(48, cb, 512));
            a0 = MFMA(f0, bw, a0); a1 = MFMA(f1, bw, a1);
            a2 = MFMA(f2, bw, a2); a3 = MFMA(f3, bw, a3);
        }
        const float bias = Bo[j];
#pragma unroll
        for (int mt = 0; mt < 4; ++mt) {
            f32x4 av = (mt == 0) ? a0 : (mt == 1) ? a1 : (mt == 2) ? a2 : a3;
#pragma unroll
            for (int r = 0; r < 4; ++r) {
                int row = mt * 16 + lg * 4 + r;
                if (row < 49) {
                    short* p = (short*)(smem + SW + swz(row, j * 2, 512));
                    *p = f2bf(bf2f(*p) + av[r] + bias);
                }
            }
        }
    }
    __syncthreads();
    {
        const int l = tid >> 3, s = tid & 7;
        if (l < 49) {
            float sum = 0.f, sq = 0.f;
            for (int ii = 0; ii < 32; ++ii) {
                int c = s * 32 + ((ii + tid) & 31);
                float v = bf2f(*(const short*)(smem + SW + swz(l, c * 2, 512)));
                sum += v; sq += v * v;
            }
#pragma unroll
            for (int m = 1; m < 8; m <<= 1) { sum += __shfl_xor(sum, m); sq += __shfl_xor(sq, m); }
            if (s == 0) {
                float mean = sum * (1.f / 256.f);
                ((float*)(smem + ST))[l * 2] = mean;
                ((float*)(smem + ST))[l * 2 + 1] = rsqrtf(sq * (1.f / 256.f) - mean * mean + 1e-5f);
            }
        }
    }
    __syncthreads();
    {
        const float* st = (const float*)(smem + ST);
        float w0 = n2w[c0], b0 = n2b[c0], w1 = n2w[c0 + 16], b1 = n2b[c0 + 16];
#pragma unroll
        for (int ct = 0; ct < 2; ++ct)
#pragma unroll
        for (int mt = 0; mt < 4; ++mt)
#pragma unroll
        for (int r = 0; r < 4; ++r) {
            int row = mt * 16 + lg * 4 + r, col = c0 + ct * 16;
            if (row < 49) {
                float v = bf2f(*(const short*)(smem + SW + swz(row, col * 2, 512)));
                float yv = (v - st[row * 2]) * st[row * 2 + 1] * (ct ? w1 : w0) + (ct ? b1 : b0);
                *(short*)(smem + OB + swz(row, col * 2, 512)) = f2bf(yv);
            }
        }
    }
    __syncthreads();
    f32x4 macc[8];
#pragma unroll
    for (int i = 0; i < 8; ++i) macc[i] = z;
#pragma unroll 1
    for (int chunk = 0; chunk < 4; ++chunk) {
#pragma unroll 1
        for (int ct = 0; ct < 2; ++ct) {
            const int lcol = c0 + ct * 16;
            const int jj = chunk * 256 + lcol;
            f32x4 a0 = z, a1 = z, a2 = z, a3 = z;
            const short* wr = W1B + (size_t)jj * 256 + lg * 8;
#pragma unroll
            for (int kk = 0; kk < 8; ++kk) {
                bf16x8 bw = *(const bf16x8*)(wr + kk * 32);
                const int cb = kk * 64 + lg * 16;
                bf16x8 f0 = *(const bf16x8*)(smem + OB + swz(l15, cb, 512));
                bf16x8 f1 = *(const bf16x8*)(smem + OB + swz(16 + l15, cb, 512));
                bf16x8 f2 = *(const bf16x8*)(smem + OB + swz(32 + l15, cb, 512));
                bf16x8 f3 = *(const bf16x8*)(smem + OB + swz(48, cb, 512));
                a0 = MFMA(f0, bw, a0); a1 = MFMA(f1, bw, a1);
                a2 = MFMA(f2, bw, a2); a3 = MFMA(f3, bw, a3);
            }
            const float bias = B1[jj];
#pragma unroll
            for (int mt = 0; mt < 4; ++mt) {
                f32x4 av = (mt == 0) ? a0 : (mt == 1) ? a1 : (mt == 2) ? a2 : a3;
#pragma unroll
                for (int r = 0; r < 4; ++r) {
                    int row = mt * 16 + lg * 4 + r;
                    if (row < 49) {
                        float v = av[r] + bias;
                        float g = 0.5f * v * (1.f + erff(v * 0.70710678118654752f));
                        *(short*)(smem + CQ + swz(row, lcol * 2, 512)) = f2bf(g);
                    }
                }
            }
        }
        __syncthreads();
#pragma unroll 1
        for (int ct = 0; ct < 2; ++ct) {
            const int j = c0 + ct * 16;
            const short* wr = W2B + (size_t)j * 1024 + chunk * 256 + lg * 8;
#pragma unroll
            for (int kk = 0; kk < 8; ++kk) {
                bf16x8 bw = *(const bf16x8*)(wr + kk * 32);
                const int cb = kk * 64 + lg * 16;
                bf16x8 f0 = *(const bf16x8*)(smem + CQ + swz(l15, cb, 512));
                bf16x8 f1 = *(const bf16x8*)(smem + CQ + swz(16 + l15, cb, 512));
                bf16x8 f2 = *(const bf16x8*)(smem + CQ + swz(32 + l15, cb, 512));
                bf16x8 f3 = *(const bf16x8*)(smem + CQ + swz(48, cb, 512));
                macc[ct * 4 + 0] = MFMA(f0, bw, macc[ct * 4 + 0]);
                macc[ct * 4 + 1] = MFMA(f1, bw, macc[ct * 4 + 1]);
                macc[ct * 4 + 2] = MFMA(f2, bw, macc[ct * 4 + 2]);
                macc[ct * 4 + 3] = MFMA(f3, bw, macc[ct * 4 + 3]);
            }
        }
        __syncthreads();
    }
    {
        float b20 = B2[c0], b21 = B2[c0 + 16];
#pragma unroll
        for (int ct = 0; ct < 2; ++ct)
#pragma unroll
        for (int mt = 0; mt < 4; ++mt)
#pragma unroll
        for (int r = 0; r < 4; ++r) {
            int row = mt * 16 + lg * 4 + r, col = c0 + ct * 16;
            if (row < 49) {
                float base = bf2f(*(const short*)(smem + SW + swz(row, col * 2, 512)));
                *(float*)(smem + row * 1024 + ((col * 4) ^ ((row & 7) << 4))) =
                    base + macc[ct * 4 + mt][r] + (ct ? b21 : b20);
            }
        }
    }
    __syncthreads();
    {
        for (int i = tid; i < 256 * 49; i += 512) {
            int c = i / 49, l = i - c * 49;
            int hh = wh * 7 + l / 7, ww = w7 * 7 + (l % 7);
            out[((size_t)(b * 256 + c) * 224 + hh) * 224 + ww] =
                *(const float*)(smem + l * 1024 + ((c * 4) ^ ((l & 7) << 4)));
        }
    }
}

extern "C" void kernel_launch(void* const* d_in, const int* in_sizes, int n_in,
                              void* d_out, int out_size, void* d_ws, size_t ws_size,
                              hipStream_t stream) {
    const float* x   = (const float*)d_in[0];
    const float* n1w = (const float*)d_in[1];
    const float* n1b = (const float*)d_in[2];
    const float* Wq  = (const float*)d_in[3];
    const float* Bq  = (const float*)d_in[4];
    const float* Wo  = (const float*)d_in[5];
    const float* Bo  = (const float*)d_in[6];
    const float* n2w = (const float*)d_in[7];
    const float* n2b = (const float*)d_in[8];
    const float* W1  = (const float*)d_in[9];
    const float* B1  = (const float*)d_in[10];
    const float* W2  = (const float*)d_in[11];
    const float* B2  = (const float*)d_in[12];
    float* out = (float*)d_out;
    (void)in_sizes; (void)n_in; (void)out_size;

    short* wsp = (short*)d_ws;
    short* WqB = wsp;                // 196608 shorts
    short* WoB = wsp + 196608;       // 65536
    short* W1B = wsp + 262144;       // 262144
    short* W2B = wsp + 524288;       // 262144  -> weights end at byte 1572864
    short* Rws = wsp + 786432;       // 401408*256 shorts = 205520896 B

    const size_t WS_NEEDED = 1572864ULL + 205520896ULL;   // ~207.1 MB

    prep_kernel<<<192, 256, 0, stream>>>(Wq, WqB, 49152);
    prep_kernel<<<64,  256, 0, stream>>>(Wo, WoB, 16384);
    prep_kernel<<<256, 256, 0, stream>>>(W1, W1B, 65536);
    prep_kernel<<<256, 256, 0, stream>>>(W2, W2B, 65536);

    if (ws_size >= WS_NEEDED) {
        swin_attn<<<8192, 512, 76288, stream>>>(x, n1w, n1b, WqB, Bq, WoB, Bo, Rws);
        mlp_kernel<<<3136, 512, 134144, stream>>>(Rws, n2w, n2b, W1B, B1, W2B, B2, out);
    } else {
        swin_mono<<<8192, 512, 76288, stream>>>(x, n1w, n1b, WqB, Bq, WoB, Bo,
                                                n2w, n2b, W1B, B1, W2B, B2, out);
    }
}